// Round 1
// 384.448 us; speedup vs baseline: 1.0532x; 1.0532x over previous
//
#include <hip/hip_runtime.h>
#include <math.h>

// ---------------------------------------------------------------------------
// GAT 2-layer + mean-pool + classifier.
//  - CSR(dst): bucketed two-pass build (multisplit) — avoids the ~16x line
//    amplification of a flat random scatter (R11 diagnosis: ~150us hidden)
//  - softmax denominators factor out; no segment-max (logits O(1), fp32 safe)
//  - message tables bf16
//  - aggregation: ONE lane-group per dst (was 2 groups splitting the list);
//    unmasked full 8-rounds + single masked tail round; 32-bit index math;
//    no cross-group shfl reduction.  (R0 theory: ~31% masked-lane waste)
//  - GEMMs: MFMA 16x16x32 bf16
// ---------------------------------------------------------------------------

typedef __attribute__((ext_vector_type(8))) short bf16x8;
typedef __attribute__((ext_vector_type(4))) float f32x4;

__device__ __forceinline__ unsigned f2bf_rne(float x){
  unsigned u = __float_as_uint(x);
  return (u + 0x7fffu + ((u >> 16) & 1u)) >> 16;
}
__device__ __forceinline__ unsigned pk_bf2(float a, float b){
  return f2bf_rne(a) | (f2bf_rne(b) << 16);
}
__device__ __forceinline__ void unpack8(uint4 q, float* f){
  f[0] = __uint_as_float(q.x << 16);
  f[1] = __uint_as_float(q.x & 0xffff0000u);
  f[2] = __uint_as_float(q.y << 16);
  f[3] = __uint_as_float(q.y & 0xffff0000u);
  f[4] = __uint_as_float(q.z << 16);
  f[5] = __uint_as_float(q.z & 0xffff0000u);
  f[6] = __uint_as_float(q.w << 16);
  f[7] = __uint_as_float(q.w & 0xffff0000u);
}

// ---------------- bucketed CSR build ----------------
// bucket b = dst >> 8 (256 dsts/bucket). NB <= 512.
// packed record: src | (dstoff << 17)  (src < 2^17, dstoff < 256)

#define CHUNKE 2048   // was 8192: 196 blocks under-filled 256 CUs; 782 now

__global__ __launch_bounds__(256) void k_bucketcount(
    const int* __restrict__ dst, int* __restrict__ bcnt, int e, int NB)
{
  __shared__ int hcnt[512];
  const int tid = threadIdx.x;
  for (int b = tid; b < 512; b += 256) hcnt[b] = 0;
  __syncthreads();
  const int lo = blockIdx.x * CHUNKE;
  const int hi = min(lo + CHUNKE, e);
  for (int i = lo + tid; i < hi; i += 256)
    atomicAdd(&hcnt[dst[i] >> 8], 1);
  __syncthreads();
  for (int b = tid; b < NB; b += 256)
    if (hcnt[b]) atomicAdd(&bcnt[b], hcnt[b]);
}

__global__ __launch_bounds__(512) void k_bucketscan(
    const int* __restrict__ bcnt, int* __restrict__ bbase,
    int* __restrict__ cur, int* __restrict__ off, int e, int n, int NB)
{
  __shared__ int sh[512];
  const int t = threadIdx.x;
  int v = (t < NB) ? bcnt[t] : 0;
  sh[t] = v;
  __syncthreads();
  for (int o = 1; o < 512; o <<= 1){
    int x = (t >= o) ? sh[t - o] : 0;
    __syncthreads();
    sh[t] += x;
    __syncthreads();
  }
  if (t < NB){
    int excl = sh[t] - v;
    bbase[t] = excl;
    cur[t]   = excl;
  }
  if (t == 0) off[n] = e;
}

__global__ __launch_bounds__(256) void k_partition(
    const int* __restrict__ src, const int* __restrict__ dst,
    int* __restrict__ cur, unsigned* __restrict__ packed, int e, int NB)
{
  __shared__ int hcnt[512];
  __shared__ int hbase[512];
  const int tid = threadIdx.x;
  for (int b = tid; b < 512; b += 256) hcnt[b] = 0;
  __syncthreads();
  const int lo = blockIdx.x * CHUNKE;
  const int hi = min(lo + CHUNKE, e);
  for (int i = lo + tid; i < hi; i += 256)
    atomicAdd(&hcnt[dst[i] >> 8], 1);
  __syncthreads();
  for (int b = tid; b < NB; b += 256){
    int c = hcnt[b];
    hbase[b] = c ? atomicAdd(&cur[b], c) : 0;
    hcnt[b] = 0;
  }
  __syncthreads();
  for (int i = lo + tid; i < hi; i += 256){
    int d = dst[i];
    int b = d >> 8;
    int p = hbase[b] + atomicAdd(&hcnt[b], 1);
    packed[p] = (unsigned)src[i] | ((unsigned)(d & 255) << 17);
  }
}

__global__ __launch_bounds__(256) void k_bucketbuild(
    const unsigned* __restrict__ packed, const int* __restrict__ bbase,
    const int* __restrict__ bcnt, int* __restrict__ off,
    int* __restrict__ csr, int n)
{
  __shared__ int lcnt[256];
  __shared__ int loff[256];
  const int b    = blockIdx.x;
  const int tid  = threadIdx.x;
  const int seg0 = bbase[b];
  const int scnt = bcnt[b];

  lcnt[tid] = 0;
  __syncthreads();
  for (int i = tid; i < scnt; i += 256)
    atomicAdd(&lcnt[packed[seg0 + i] >> 17], 1);
  __syncthreads();
  int v = lcnt[tid];
  loff[tid] = v;
  __syncthreads();
  for (int o = 1; o < 256; o <<= 1){
    int x = (tid >= o) ? loff[tid - o] : 0;
    __syncthreads();
    loff[tid] += x;
    __syncthreads();
  }
  int excl = loff[tid] - v;
  __syncthreads();
  loff[tid] = excl;              // exclusive local offsets
  lcnt[tid] = 0;                 // reuse as cursor
  int d = (b << 8) + tid;
  if (d < n) off[d] = seg0 + excl;
  __syncthreads();
  for (int i = tid; i < scnt; i += 256){
    unsigned rec = packed[seg0 + i];
    int doff = rec >> 17;
    int s    = rec & 0x1FFFF;
    int p    = atomicAdd(&lcnt[doff], 1);
    csr[seg0 + loff[doff] + p] = s;
  }
}

// ---------------- MFMA GEMM (X @ W) + attention dot epilogue ----------------

template<int OUTC, int HEADS, bool XBF16, typename XT>
__global__ __launch_bounds__(256) void k_gemm_mfma(
    const XT* __restrict__ X, const float* __restrict__ W,
    const float* __restrict__ att_s, const float* __restrict__ att_d,
    unsigned short* __restrict__ H, float* __restrict__ ASRC,
    float* __restrict__ ADST, int n)
{
  constexpr int K  = 128;
  constexpr int KC = 32;
  constexpr int CT = OUTC / 16;
  constexpr int RT = 16 / CT;
  constexpr int WROWS = RT * 16;
  constexpr int BROWS = WROWS * 4;

  __shared__ unsigned short Bs[OUTC][K + 8];
  __shared__ unsigned short As[BROWS][KC + 8];

  const int tid   = threadIdx.x;
  const int lane  = tid & 63;
  const int c15   = lane & 15;
  const int quad  = lane >> 4;
  const int warow = (tid >> 6) * WROWS;
  const int row0  = blockIdx.x * BROWS;

  f32x4 acc[CT][RT];
  #pragma unroll
  for (int ct = 0; ct < CT; ++ct)
    #pragma unroll
    for (int t = 0; t < RT; ++t)
      #pragma unroll
      for (int r = 0; r < 4; ++r) acc[ct][t][r] = 0.f;

  for (int idx = tid; idx < K * OUTC / 4; idx += 256){
    int k  = idx / (OUTC / 4);
    int c4 = (idx % (OUTC / 4)) * 4;
    float4 v = *(const float4*)&W[(size_t)k * OUTC + c4];
    Bs[c4 + 0][k] = (unsigned short)f2bf_rne(v.x);
    Bs[c4 + 1][k] = (unsigned short)f2bf_rne(v.y);
    Bs[c4 + 2][k] = (unsigned short)f2bf_rne(v.z);
    Bs[c4 + 3][k] = (unsigned short)f2bf_rne(v.w);
  }

  for (int kc = 0; kc < K; kc += KC){
    if (XBF16){
      for (int idx = tid; idx < BROWS * (KC / 8); idx += 256){
        int rr = idx / (KC / 8);
        int q  = idx % (KC / 8);
        int row = row0 + rr;
        uint4 v = make_uint4(0, 0, 0, 0);
        if (row < n) v = *(const uint4*)((const unsigned short*)X + (size_t)row * K + kc + q * 8);
        *(uint4*)&As[rr][q * 8] = v;
      }
    } else {
      for (int idx = tid; idx < BROWS * (KC / 4); idx += 256){
        int rr = idx / (KC / 4);
        int q  = idx % (KC / 4);
        int row = row0 + rr;
        float4 v = make_float4(0.f, 0.f, 0.f, 0.f);
        if (row < n) v = *(const float4*)((const float*)X + (size_t)row * K + kc + q * 4);
        *(uint2*)&As[rr][q * 4] = make_uint2(pk_bf2(v.x, v.y), pk_bf2(v.z, v.w));
      }
    }
    __syncthreads();

    bf16x8 af[RT];
    #pragma unroll
    for (int t = 0; t < RT; ++t)
      af[t] = *(const bf16x8*)&As[warow + t * 16 + c15][8 * quad];
    #pragma unroll
    for (int ct = 0; ct < CT; ++ct){
      bf16x8 bfr = *(const bf16x8*)&Bs[ct * 16 + c15][kc + 8 * quad];
      #pragma unroll
      for (int t = 0; t < RT; ++t)
        acc[ct][t] = __builtin_amdgcn_mfma_f32_16x16x32_bf16(af[t], bfr, acc[ct][t], 0, 0, 0);
    }
    __syncthreads();
  }

  float ats[CT], atd[CT];
  #pragma unroll
  for (int ct = 0; ct < CT; ++ct){
    ats[ct] = att_s[ct * 16 + c15];
    atd[ct] = att_d[ct * 16 + c15];
  }
  #pragma unroll
  for (int t = 0; t < RT; ++t){
    #pragma unroll
    for (int r = 0; r < 4; ++r){
      int row = row0 + warow + t * 16 + quad * 4 + r;
      float hs[HEADS], hd[HEADS];
      #pragma unroll
      for (int h = 0; h < HEADS; ++h){ hs[h] = 0.f; hd[h] = 0.f; }
      #pragma unroll
      for (int ct = 0; ct < CT; ++ct){
        float v = acc[ct][t][r];
        constexpr int CPH = OUTC / HEADS;
        int h = (ct * 16) / CPH;
        hs[h] = fmaf(v, ats[ct], hs[h]);
        hd[h] = fmaf(v, atd[ct], hd[h]);
      }
      #pragma unroll
      for (int h = 0; h < HEADS; ++h){
        #pragma unroll
        for (int s = 1; s < 16; s <<= 1){
          hs[h] += __shfl_xor(hs[h], s);
          hd[h] += __shfl_xor(hd[h], s);
        }
      }
      if (row < n){
        #pragma unroll
        for (int ct = 0; ct < CT; ++ct)
          H[(size_t)row * OUTC + ct * 16 + c15] = (unsigned short)f2bf_rne(acc[ct][t][r]);
        if (c15 == 0){
          #pragma unroll
          for (int h = 0; h < HEADS; ++h){
            ASRC[(size_t)row * HEADS + h] = hs[h];
            ADST[(size_t)row * HEADS + h] = hd[h];
          }
        }
      }
    }
  }
}

// ---------------- dst-centric aggregation + bias + ELU ----------------
// One CL-lane group owns ONE dst: self-loop init, unmasked full 8-rounds,
// one masked tail round, per-lane finalize. No cross-group reduction.

template<int CH, int HEADS, bool OUTBF16>
__global__ __launch_bounds__(256) void k_aggregate(
    const unsigned short* __restrict__ Hmsg, const float* __restrict__ ASRC,
    const float* __restrict__ ADST, const int* __restrict__ off,
    const int* __restrict__ csr, const float* __restrict__ bias,
    void* __restrict__ OUT, int n)
{
  constexpr int CL  = CH / 8;       // lanes per dst (16 for CH=128, 8 for CH=64)
  constexpr int DPB = 256 / CL;     // dsts per block
  constexpr int CPH = CH / HEADS;
  constexpr int RQ  = CH / 8;       // uint4 per bf16 row

  const int tid = threadIdx.x;
  const int ld  = tid / CL;
  const int cl  = tid % CL;
  const int c0  = cl * 8;
  const int h   = c0 / CPH;
  const int d   = blockIdx.x * DPB + ld;
  if (d >= n) return;

  const uint4* Hv = (const uint4*)Hmsg;
  const float adst = ADST[d * HEADS + h];

  // self-loop contribution (PyG adds self-loops)
  float acc[8];
  float wsum;
  {
    float t = ASRC[d * HEADS + h] + adst;
    float w = __expf(fmaxf(t, 0.2f * t));
    float f[8];
    unpack8(Hv[d * RQ + cl], f);
    #pragma unroll
    for (int j = 0; j < 8; ++j) acc[j] = w * f[j];
    wsum = w;
  }

  const int s0   = off[d];
  const int cnt  = off[d + 1] - s0;
  const int full = cnt & ~7;

  for (int p = 0; p < full; p += 8){
    int idx[8];
    #pragma unroll
    for (int j = 0; j < 8; ++j) idx[j] = csr[s0 + p + j];
    float av[8];
    #pragma unroll
    for (int j = 0; j < 8; ++j) av[j] = ASRC[idx[j] * HEADS + h];
    uint4 hq[8];
    #pragma unroll
    for (int j = 0; j < 8; ++j) hq[j] = Hv[idx[j] * RQ + cl];
    #pragma unroll
    for (int j = 0; j < 8; ++j){
      float t = av[j] + adst;
      float w = __expf(fmaxf(t, 0.2f * t));
      float f[8];
      unpack8(hq[j], f);
      #pragma unroll
      for (int q = 0; q < 8; ++q) acc[q] = fmaf(w, f[q], acc[q]);
      wsum += w;
    }
  }

  const int rem = cnt - full;
  if (rem){
    int  idx[8];
    bool ok[8];
    #pragma unroll
    for (int j = 0; j < 8; ++j){
      int q = csr[s0 + full + j];     // csr has +8 slack
      ok[j]  = j < rem;
      idx[j] = ok[j] ? q : 0;
    }
    float av[8];
    #pragma unroll
    for (int j = 0; j < 8; ++j) av[j] = ASRC[idx[j] * HEADS + h];
    uint4 hq[8];
    #pragma unroll
    for (int j = 0; j < 8; ++j) hq[j] = Hv[idx[j] * RQ + cl];
    #pragma unroll
    for (int j = 0; j < 8; ++j){
      float t = av[j] + adst;
      float w = __expf(fmaxf(t, 0.2f * t));
      w = ok[j] ? w : 0.f;
      float f[8];
      unpack8(hq[j], f);
      #pragma unroll
      for (int q = 0; q < 8; ++q) acc[q] = fmaf(w, f[q], acc[q]);
      wsum += w;
    }
  }

  const float inv = 1.f / (wsum + 1e-16f);
  float o[8];
  #pragma unroll
  for (int j = 0; j < 8; ++j){
    float v = acc[j] * inv + bias[c0 + j];
    o[j] = v > 0.f ? v : expm1f(v);
  }
  if (OUTBF16){
    uint4 q;
    q.x = pk_bf2(o[0], o[1]); q.y = pk_bf2(o[2], o[3]);
    q.z = pk_bf2(o[4], o[5]); q.w = pk_bf2(o[6], o[7]);
    *(uint4*)((unsigned short*)OUT + (size_t)d * CH + c0) = q;
  } else {
    float* Of = (float*)OUT;
    *(float4*)&Of[(size_t)d * CH + c0 + 0] = make_float4(o[0], o[1], o[2], o[3]);
    *(float4*)&Of[(size_t)d * CH + c0 + 4] = make_float4(o[4], o[5], o[6], o[7]);
  }
}

// ---------------- pooling: chunk-parallel partial sums ----------------

__global__ __launch_bounds__(256) void k_pool_partial(
    const float* __restrict__ H, const int* __restrict__ batch,
    float* __restrict__ sums, int n)
{
  constexpr int CHUNK = 256;
  const int c    = threadIdx.x & 63;
  const int slot = threadIdx.x >> 6;
  const int start = blockIdx.x * CHUNK;
  const int end   = min(start + CHUNK, n);

  float acc = 0.f;
  int cur = -1;
  for (int nn = start + slot; nn < end; nn += 4){
    int g = batch[nn];
    if (g != cur){
      if (cur >= 0) atomicAdd(&sums[cur * 64 + c], acc);
      acc = 0.f; cur = g;
    }
    acc += H[(size_t)nn * 64 + c];
  }
  if (cur >= 0) atomicAdd(&sums[cur * 64 + c], acc);
}

__global__ __launch_bounds__(128) void k_classify(
    const float* __restrict__ sums, const int* __restrict__ batch,
    const float* __restrict__ Wc, const float* __restrict__ bc,
    float* __restrict__ out, int n)
{
  int t = threadIdx.x;
  if (t >= 128) return;
  int g = t >> 1, cls = t & 1;
  int lo = 0, hi = n;
  while (lo < hi){ int m = (lo + hi) >> 1; if (batch[m] < g) lo = m + 1; else hi = m; }
  int s = lo;
  lo = s; hi = n;
  while (lo < hi){ int m = (lo + hi) >> 1; if (batch[m] < g + 1) lo = m + 1; else hi = m; }
  int cnt = lo - s;
  float inv = 1.f / (float)(cnt > 1 ? cnt : 1);
  float dot = 0.f;
  #pragma unroll
  for (int c = 0; c < 64; ++c) dot = fmaf(sums[g * 64 + c], Wc[c * 2 + cls], dot);
  out[g * 2 + cls] = dot * inv + bc[cls];
}

// ---------------- launch ----------------

extern "C" void kernel_launch(void* const* d_in, const int* in_sizes, int n_in,
                              void* d_out, int out_size, void* d_ws, size_t ws_size,
                              hipStream_t stream)
{
  const float* x    = (const float*)d_in[0];
  const int*   edge = (const int*)  d_in[1];
  const int*   batch= (const int*)  d_in[2];
  const float* W1   = (const float*)d_in[3];
  const float* as1w = (const float*)d_in[4];
  const float* ad1w = (const float*)d_in[5];
  const float* b1   = (const float*)d_in[6];
  const float* W2   = (const float*)d_in[7];
  const float* as2w = (const float*)d_in[8];
  const float* ad2w = (const float*)d_in[9];
  const float* b2   = (const float*)d_in[10];
  const float* Wc   = (const float*)d_in[11];
  const float* bc   = (const float*)d_in[12];

  const int n = in_sizes[2];          // 100000
  const int e = in_sizes[1] / 2;      // 1600000
  const int* esrc = edge;
  const int* edst = edge + e;
  const int NB = (n + 255) >> 8;      // 391 buckets

  // workspace layout
  unsigned short* h1  = (unsigned short*)d_ws;              // n*128 bf16 (later h2 n*64)
  unsigned short* h1a = h1 + (size_t)n * 128;               // n*128 bf16 (later h2a n*64 f32)
  float* as1 = (float*)(h1a + (size_t)n * 128);             // n*4
  float* ad1 = as1 + (size_t)n * 4;                         // n*4
  float* as2 = ad1 + (size_t)n * 4;                         // n
  float* ad2 = as2 + (size_t)n;                             // n
  float* sums = ad2 + (size_t)n;                            // 64*64
  int*  bcnt  = (int*)(sums + 64 * 64);                     // 512 (zeroed w/ sums)
  int*  cur   = bcnt + 512;                                 // 512
  int*  bbase = cur + 512;                                  // 512
  int*  off   = bbase + 512;                                // n+1
  unsigned* packed = (unsigned*)(off + n + 1);              // e
  int*  csr   = (int*)(packed + e);                         // e + 8 slack

  const int eb = (e + CHUNKE - 1) / CHUNKE;                 // 782 blocks

  // CSR build (bucketed two-pass)
  hipMemsetAsync(sums, 0, (64 * 64 + 512) * 4, stream);     // sums + bcnt
  k_bucketcount<<<eb, 256, 0, stream>>>(edst, bcnt, e, NB);
  k_bucketscan <<<1, 512, 0, stream>>>(bcnt, bbase, cur, off, e, n, NB);
  k_partition  <<<eb, 256, 0, stream>>>(esrc, edst, cur, packed, e, NB);
  k_bucketbuild<<<NB, 256, 0, stream>>>(packed, bbase, bcnt, off, csr, n);

  // conv1 (MFMA gemm: 128 rows/block)
  k_gemm_mfma<128, 4, false><<<(n + 127) / 128, 256, 0, stream>>>(
      x, W1, as1w, ad1w, h1, as1, ad1, n);
  k_aggregate<128, 4, true><<<(n + 15) / 16, 256, 0, stream>>>(
      h1, as1, ad1, off, csr, b1, (void*)h1a, n);

  // conv2 (MFMA gemm: 256 rows/block; region reuse)
  unsigned short* h2 = h1;
  float* h2a = (float*)h1a;
  k_gemm_mfma<64, 1, true><<<(n + 255) / 256, 256, 0, stream>>>(
      h1a, W2, as2w, ad2w, h2, as2, ad2, n);
  k_aggregate<64, 1, false><<<(n + 31) / 32, 256, 0, stream>>>(
      h2, as2, ad2, off, csr, b2, (void*)h2a, n);

  // pool + classify
  k_pool_partial<<<(n + 255) / 256, 256, 0, stream>>>(h2a, batch, sums, n);
  k_classify<<<1, 128, 0, stream>>>(sums, batch, Wc, bc, (float*)d_out, n);
}

// Round 2
// 376.296 us; speedup vs baseline: 1.0760x; 1.0217x over previous
//
#include <hip/hip_runtime.h>
#include <math.h>

// ---------------------------------------------------------------------------
// GAT 2-layer + mean-pool + classifier.
//  - CSR(dst): bucketed two-pass build (multisplit).
//    R2: k_partition stages the chunk in LDS, sorts by bucket locally, and
//    writes `packed` fully coalesced (R1 regression diagnosis: scattered
//    4B-granule runs caused RFO/writeback amplification).
//  - softmax denominators factor out; no segment-max (logits O(1), fp32 safe)
//  - message tables bf16
//  - aggregation: ONE lane-group per dst, unmasked full 8-rounds + masked
//    tail round, 32-bit index math (R1: 98->79.5us, at ~3.4 TB/s gather)
//  - GEMMs: MFMA 16x16x32 bf16
// ---------------------------------------------------------------------------

typedef __attribute__((ext_vector_type(8))) short bf16x8;
typedef __attribute__((ext_vector_type(4))) float f32x4;

__device__ __forceinline__ unsigned f2bf_rne(float x){
  unsigned u = __float_as_uint(x);
  return (u + 0x7fffu + ((u >> 16) & 1u)) >> 16;
}
__device__ __forceinline__ unsigned pk_bf2(float a, float b){
  return f2bf_rne(a) | (f2bf_rne(b) << 16);
}
__device__ __forceinline__ void unpack8(uint4 q, float* f){
  f[0] = __uint_as_float(q.x << 16);
  f[1] = __uint_as_float(q.x & 0xffff0000u);
  f[2] = __uint_as_float(q.y << 16);
  f[3] = __uint_as_float(q.y & 0xffff0000u);
  f[4] = __uint_as_float(q.z << 16);
  f[5] = __uint_as_float(q.z & 0xffff0000u);
  f[6] = __uint_as_float(q.w << 16);
  f[7] = __uint_as_float(q.w & 0xffff0000u);
}

// ---------------- bucketed CSR build ----------------
// bucket b = dst >> 8 (256 dsts/bucket). NB <= 512.
// packed record: src | (dstoff << 17)  (src < 2^17, dstoff < 256)

#define CHUNKE 8192   // back to 8192: bucket-runs of ~21 entries, and the
                      // LDS-staged partition writes them coalesced anyway

__global__ __launch_bounds__(256) void k_bucketcount(
    const int* __restrict__ dst, int* __restrict__ bcnt, int e, int NB)
{
  __shared__ int hcnt[512];
  const int tid = threadIdx.x;
  for (int b = tid; b < 512; b += 256) hcnt[b] = 0;
  __syncthreads();
  const int lo = blockIdx.x * CHUNKE;
  const int hi = min(lo + CHUNKE, e);
  for (int i = lo + tid; i < hi; i += 256)
    atomicAdd(&hcnt[dst[i] >> 8], 1);
  __syncthreads();
  for (int b = tid; b < NB; b += 256)
    if (hcnt[b]) atomicAdd(&bcnt[b], hcnt[b]);
}

__global__ __launch_bounds__(512) void k_bucketscan(
    const int* __restrict__ bcnt, int* __restrict__ bbase,
    int* __restrict__ cur, int* __restrict__ off, int e, int n, int NB)
{
  __shared__ int sh[512];
  const int t = threadIdx.x;
  int v = (t < NB) ? bcnt[t] : 0;
  sh[t] = v;
  __syncthreads();
  for (int o = 1; o < 512; o <<= 1){
    int x = (t >= o) ? sh[t - o] : 0;
    __syncthreads();
    sh[t] += x;
    __syncthreads();
  }
  if (t < NB){
    int excl = sh[t] - v;
    bbase[t] = excl;
    cur[t]   = excl;
  }
  if (t == 0) off[n] = e;
}

// LDS-staged multisplit partition: histogram -> block scan -> LDS scatter
// by bucket -> fully coalesced global writeout of the bucket-sorted chunk.
__global__ __launch_bounds__(256) void k_partition(
    const int* __restrict__ src, const int* __restrict__ dst,
    int* __restrict__ cur, unsigned* __restrict__ packed, int e, int NB)
{
  __shared__ unsigned       recs[CHUNKE];   // 32 KB  bucket-sorted records
  __shared__ unsigned short bkt[CHUNKE];    // 16 KB  bucket id per slot
  __shared__ int hcnt[512];                 // counts, then cursors
  __shared__ int hoff[512];                 // inclusive scan -> exclusive offs
  __shared__ int hbase[512];                // global base per bucket

  const int tid = threadIdx.x;
  const int lo  = blockIdx.x * CHUNKE;
  const int hi  = min(lo + CHUNKE, e);
  const int cnt = hi - lo;

  hcnt[tid] = 0; hcnt[tid + 256] = 0;
  __syncthreads();
  for (int i = lo + tid; i < hi; i += 256)
    atomicAdd(&hcnt[dst[i] >> 8], 1);
  __syncthreads();

  // inclusive scan of 512 bins with 256 threads (2 bins/thread)
  hoff[tid] = hcnt[tid]; hoff[tid + 256] = hcnt[tid + 256];
  __syncthreads();
  for (int o = 1; o < 512; o <<= 1){
    int x0 = (tid >= o)       ? hoff[tid - o]       : 0;
    int x1 = (tid + 256 >= o) ? hoff[tid + 256 - o] : 0;
    __syncthreads();
    hoff[tid] += x0; hoff[tid + 256] += x1;
    __syncthreads();
  }

  // reserve global space per bucket; convert hoff to exclusive; zero cursors
  int c0 = hcnt[tid], c1 = hcnt[tid + 256];
  int e0 = hoff[tid] - c0, e1 = hoff[tid + 256] - c1;
  hbase[tid]       = c0 ? atomicAdd(&cur[tid], c0)       : 0;
  hbase[tid + 256] = c1 ? atomicAdd(&cur[tid + 256], c1) : 0;
  __syncthreads();
  hoff[tid] = e0; hoff[tid + 256] = e1;
  hcnt[tid] = 0;  hcnt[tid + 256] = 0;
  __syncthreads();

  // LDS scatter: place records bucket-sorted
  for (int i = lo + tid; i < hi; i += 256){
    int d = dst[i];
    int b = d >> 8;
    int p = hoff[b] + atomicAdd(&hcnt[b], 1);
    recs[p] = (unsigned)src[i] | ((unsigned)(d & 255) << 17);
    bkt[p]  = (unsigned short)b;
  }
  __syncthreads();

  // coalesced writeout: consecutive t -> consecutive global addr within run
  for (int t = tid; t < cnt; t += 256){
    int b = bkt[t];
    packed[hbase[b] + t - hoff[b]] = recs[t];
  }
}

__global__ __launch_bounds__(256) void k_bucketbuild(
    const unsigned* __restrict__ packed, const int* __restrict__ bbase,
    const int* __restrict__ bcnt, int* __restrict__ off,
    int* __restrict__ csr, int n)
{
  __shared__ int lcnt[256];
  __shared__ int loff[256];
  const int b    = blockIdx.x;
  const int tid  = threadIdx.x;
  const int seg0 = bbase[b];
  const int scnt = bcnt[b];

  lcnt[tid] = 0;
  __syncthreads();
  for (int i = tid; i < scnt; i += 256)
    atomicAdd(&lcnt[packed[seg0 + i] >> 17], 1);
  __syncthreads();
  int v = lcnt[tid];
  loff[tid] = v;
  __syncthreads();
  for (int o = 1; o < 256; o <<= 1){
    int x = (tid >= o) ? loff[tid - o] : 0;
    __syncthreads();
    loff[tid] += x;
    __syncthreads();
  }
  int excl = loff[tid] - v;
  __syncthreads();
  loff[tid] = excl;              // exclusive local offsets
  lcnt[tid] = 0;                 // reuse as cursor
  int d = (b << 8) + tid;
  if (d < n) off[d] = seg0 + excl;
  __syncthreads();
  for (int i = tid; i < scnt; i += 256){
    unsigned rec = packed[seg0 + i];
    int doff = rec >> 17;
    int s    = rec & 0x1FFFF;
    int p    = atomicAdd(&lcnt[doff], 1);
    csr[seg0 + loff[doff] + p] = s;
  }
}

// ---------------- MFMA GEMM (X @ W) + attention dot epilogue ----------------

template<int OUTC, int HEADS, bool XBF16, typename XT>
__global__ __launch_bounds__(256) void k_gemm_mfma(
    const XT* __restrict__ X, const float* __restrict__ W,
    const float* __restrict__ att_s, const float* __restrict__ att_d,
    unsigned short* __restrict__ H, float* __restrict__ ASRC,
    float* __restrict__ ADST, int n)
{
  constexpr int K  = 128;
  constexpr int KC = 32;
  constexpr int CT = OUTC / 16;
  constexpr int RT = 16 / CT;
  constexpr int WROWS = RT * 16;
  constexpr int BROWS = WROWS * 4;

  __shared__ unsigned short Bs[OUTC][K + 8];
  __shared__ unsigned short As[BROWS][KC + 8];

  const int tid   = threadIdx.x;
  const int lane  = tid & 63;
  const int c15   = lane & 15;
  const int quad  = lane >> 4;
  const int warow = (tid >> 6) * WROWS;
  const int row0  = blockIdx.x * BROWS;

  f32x4 acc[CT][RT];
  #pragma unroll
  for (int ct = 0; ct < CT; ++ct)
    #pragma unroll
    for (int t = 0; t < RT; ++t)
      #pragma unroll
      for (int r = 0; r < 4; ++r) acc[ct][t][r] = 0.f;

  for (int idx = tid; idx < K * OUTC / 4; idx += 256){
    int k  = idx / (OUTC / 4);
    int c4 = (idx % (OUTC / 4)) * 4;
    float4 v = *(const float4*)&W[(size_t)k * OUTC + c4];
    Bs[c4 + 0][k] = (unsigned short)f2bf_rne(v.x);
    Bs[c4 + 1][k] = (unsigned short)f2bf_rne(v.y);
    Bs[c4 + 2][k] = (unsigned short)f2bf_rne(v.z);
    Bs[c4 + 3][k] = (unsigned short)f2bf_rne(v.w);
  }

  for (int kc = 0; kc < K; kc += KC){
    if (XBF16){
      for (int idx = tid; idx < BROWS * (KC / 8); idx += 256){
        int rr = idx / (KC / 8);
        int q  = idx % (KC / 8);
        int row = row0 + rr;
        uint4 v = make_uint4(0, 0, 0, 0);
        if (row < n) v = *(const uint4*)((const unsigned short*)X + (size_t)row * K + kc + q * 8);
        *(uint4*)&As[rr][q * 8] = v;
      }
    } else {
      for (int idx = tid; idx < BROWS * (KC / 4); idx += 256){
        int rr = idx / (KC / 4);
        int q  = idx % (KC / 4);
        int row = row0 + rr;
        float4 v = make_float4(0.f, 0.f, 0.f, 0.f);
        if (row < n) v = *(const float4*)((const float*)X + (size_t)row * K + kc + q * 4);
        *(uint2*)&As[rr][q * 4] = make_uint2(pk_bf2(v.x, v.y), pk_bf2(v.z, v.w));
      }
    }
    __syncthreads();

    bf16x8 af[RT];
    #pragma unroll
    for (int t = 0; t < RT; ++t)
      af[t] = *(const bf16x8*)&As[warow + t * 16 + c15][8 * quad];
    #pragma unroll
    for (int ct = 0; ct < CT; ++ct){
      bf16x8 bfr = *(const bf16x8*)&Bs[ct * 16 + c15][kc + 8 * quad];
      #pragma unroll
      for (int t = 0; t < RT; ++t)
        acc[ct][t] = __builtin_amdgcn_mfma_f32_16x16x32_bf16(af[t], bfr, acc[ct][t], 0, 0, 0);
    }
    __syncthreads();
  }

  float ats[CT], atd[CT];
  #pragma unroll
  for (int ct = 0; ct < CT; ++ct){
    ats[ct] = att_s[ct * 16 + c15];
    atd[ct] = att_d[ct * 16 + c15];
  }
  #pragma unroll
  for (int t = 0; t < RT; ++t){
    #pragma unroll
    for (int r = 0; r < 4; ++r){
      int row = row0 + warow + t * 16 + quad * 4 + r;
      float hs[HEADS], hd[HEADS];
      #pragma unroll
      for (int h = 0; h < HEADS; ++h){ hs[h] = 0.f; hd[h] = 0.f; }
      #pragma unroll
      for (int ct = 0; ct < CT; ++ct){
        float v = acc[ct][t][r];
        constexpr int CPH = OUTC / HEADS;
        int h = (ct * 16) / CPH;
        hs[h] = fmaf(v, ats[ct], hs[h]);
        hd[h] = fmaf(v, atd[ct], hd[h]);
      }
      #pragma unroll
      for (int h = 0; h < HEADS; ++h){
        #pragma unroll
        for (int s = 1; s < 16; s <<= 1){
          hs[h] += __shfl_xor(hs[h], s);
          hd[h] += __shfl_xor(hd[h], s);
        }
      }
      if (row < n){
        #pragma unroll
        for (int ct = 0; ct < CT; ++ct)
          H[(size_t)row * OUTC + ct * 16 + c15] = (unsigned short)f2bf_rne(acc[ct][t][r]);
        if (c15 == 0){
          #pragma unroll
          for (int h = 0; h < HEADS; ++h){
            ASRC[(size_t)row * HEADS + h] = hs[h];
            ADST[(size_t)row * HEADS + h] = hd[h];
          }
        }
      }
    }
  }
}

// ---------------- dst-centric aggregation + bias + ELU ----------------
// One CL-lane group owns ONE dst: self-loop init, unmasked full 8-rounds,
// one masked tail round, per-lane finalize. No cross-group reduction.

template<int CH, int HEADS, bool OUTBF16>
__global__ __launch_bounds__(256) void k_aggregate(
    const unsigned short* __restrict__ Hmsg, const float* __restrict__ ASRC,
    const float* __restrict__ ADST, const int* __restrict__ off,
    const int* __restrict__ csr, const float* __restrict__ bias,
    void* __restrict__ OUT, int n)
{
  constexpr int CL  = CH / 8;       // lanes per dst (16 for CH=128, 8 for CH=64)
  constexpr int DPB = 256 / CL;     // dsts per block
  constexpr int CPH = CH / HEADS;
  constexpr int RQ  = CH / 8;       // uint4 per bf16 row

  const int tid = threadIdx.x;
  const int ld  = tid / CL;
  const int cl  = tid % CL;
  const int c0  = cl * 8;
  const int h   = c0 / CPH;
  const int d   = blockIdx.x * DPB + ld;
  if (d >= n) return;

  const uint4* Hv = (const uint4*)Hmsg;
  const float adst = ADST[d * HEADS + h];

  // self-loop contribution (PyG adds self-loops)
  float acc[8];
  float wsum;
  {
    float t = ASRC[d * HEADS + h] + adst;
    float w = __expf(fmaxf(t, 0.2f * t));
    float f[8];
    unpack8(Hv[d * RQ + cl], f);
    #pragma unroll
    for (int j = 0; j < 8; ++j) acc[j] = w * f[j];
    wsum = w;
  }

  const int s0   = off[d];
  const int cnt  = off[d + 1] - s0;
  const int full = cnt & ~7;

  for (int p = 0; p < full; p += 8){
    int idx[8];
    #pragma unroll
    for (int j = 0; j < 8; ++j) idx[j] = csr[s0 + p + j];
    float av[8];
    #pragma unroll
    for (int j = 0; j < 8; ++j) av[j] = ASRC[idx[j] * HEADS + h];
    uint4 hq[8];
    #pragma unroll
    for (int j = 0; j < 8; ++j) hq[j] = Hv[idx[j] * RQ + cl];
    #pragma unroll
    for (int j = 0; j < 8; ++j){
      float t = av[j] + adst;
      float w = __expf(fmaxf(t, 0.2f * t));
      float f[8];
      unpack8(hq[j], f);
      #pragma unroll
      for (int q = 0; q < 8; ++q) acc[q] = fmaf(w, f[q], acc[q]);
      wsum += w;
    }
  }

  const int rem = cnt - full;
  if (rem){
    int  idx[8];
    bool ok[8];
    #pragma unroll
    for (int j = 0; j < 8; ++j){
      int q = csr[s0 + full + j];     // csr has +8 slack
      ok[j]  = j < rem;
      idx[j] = ok[j] ? q : 0;
    }
    float av[8];
    #pragma unroll
    for (int j = 0; j < 8; ++j) av[j] = ASRC[idx[j] * HEADS + h];
    uint4 hq[8];
    #pragma unroll
    for (int j = 0; j < 8; ++j) hq[j] = Hv[idx[j] * RQ + cl];
    #pragma unroll
    for (int j = 0; j < 8; ++j){
      float t = av[j] + adst;
      float w = __expf(fmaxf(t, 0.2f * t));
      w = ok[j] ? w : 0.f;
      float f[8];
      unpack8(hq[j], f);
      #pragma unroll
      for (int q = 0; q < 8; ++q) acc[q] = fmaf(w, f[q], acc[q]);
      wsum += w;
    }
  }

  const float inv = 1.f / (wsum + 1e-16f);
  float o[8];
  #pragma unroll
  for (int j = 0; j < 8; ++j){
    float v = acc[j] * inv + bias[c0 + j];
    o[j] = v > 0.f ? v : expm1f(v);
  }
  if (OUTBF16){
    uint4 q;
    q.x = pk_bf2(o[0], o[1]); q.y = pk_bf2(o[2], o[3]);
    q.z = pk_bf2(o[4], o[5]); q.w = pk_bf2(o[6], o[7]);
    *(uint4*)((unsigned short*)OUT + (size_t)d * CH + c0) = q;
  } else {
    float* Of = (float*)OUT;
    *(float4*)&Of[(size_t)d * CH + c0 + 0] = make_float4(o[0], o[1], o[2], o[3]);
    *(float4*)&Of[(size_t)d * CH + c0 + 4] = make_float4(o[4], o[5], o[6], o[7]);
  }
}

// ---------------- pooling: chunk-parallel partial sums ----------------

__global__ __launch_bounds__(256) void k_pool_partial(
    const float* __restrict__ H, const int* __restrict__ batch,
    float* __restrict__ sums, int n)
{
  constexpr int CHUNK = 256;
  const int c    = threadIdx.x & 63;
  const int slot = threadIdx.x >> 6;
  const int start = blockIdx.x * CHUNK;
  const int end   = min(start + CHUNK, n);

  float acc = 0.f;
  int cur = -1;
  for (int nn = start + slot; nn < end; nn += 4){
    int g = batch[nn];
    if (g != cur){
      if (cur >= 0) atomicAdd(&sums[cur * 64 + c], acc);
      acc = 0.f; cur = g;
    }
    acc += H[(size_t)nn * 64 + c];
  }
  if (cur >= 0) atomicAdd(&sums[cur * 64 + c], acc);
}

__global__ __launch_bounds__(128) void k_classify(
    const float* __restrict__ sums, const int* __restrict__ batch,
    const float* __restrict__ Wc, const float* __restrict__ bc,
    float* __restrict__ out, int n)
{
  int t = threadIdx.x;
  if (t >= 128) return;
  int g = t >> 1, cls = t & 1;
  int lo = 0, hi = n;
  while (lo < hi){ int m = (lo + hi) >> 1; if (batch[m] < g) lo = m + 1; else hi = m; }
  int s = lo;
  lo = s; hi = n;
  while (lo < hi){ int m = (lo + hi) >> 1; if (batch[m] < g + 1) lo = m + 1; else hi = m; }
  int cnt = lo - s;
  float inv = 1.f / (float)(cnt > 1 ? cnt : 1);
  float dot = 0.f;
  #pragma unroll
  for (int c = 0; c < 64; ++c) dot = fmaf(sums[g * 64 + c], Wc[c * 2 + cls], dot);
  out[g * 2 + cls] = dot * inv + bc[cls];
}

// ---------------- launch ----------------

extern "C" void kernel_launch(void* const* d_in, const int* in_sizes, int n_in,
                              void* d_out, int out_size, void* d_ws, size_t ws_size,
                              hipStream_t stream)
{
  const float* x    = (const float*)d_in[0];
  const int*   edge = (const int*)  d_in[1];
  const int*   batch= (const int*)  d_in[2];
  const float* W1   = (const float*)d_in[3];
  const float* as1w = (const float*)d_in[4];
  const float* ad1w = (const float*)d_in[5];
  const float* b1   = (const float*)d_in[6];
  const float* W2   = (const float*)d_in[7];
  const float* as2w = (const float*)d_in[8];
  const float* ad2w = (const float*)d_in[9];
  const float* b2   = (const float*)d_in[10];
  const float* Wc   = (const float*)d_in[11];
  const float* bc   = (const float*)d_in[12];

  const int n = in_sizes[2];          // 100000
  const int e = in_sizes[1] / 2;      // 1600000
  const int* esrc = edge;
  const int* edst = edge + e;
  const int NB = (n + 255) >> 8;      // 391 buckets

  // workspace layout
  unsigned short* h1  = (unsigned short*)d_ws;              // n*128 bf16 (later h2 n*64)
  unsigned short* h1a = h1 + (size_t)n * 128;               // n*128 bf16 (later h2a n*64 f32)
  float* as1 = (float*)(h1a + (size_t)n * 128);             // n*4
  float* ad1 = as1 + (size_t)n * 4;                         // n*4
  float* as2 = ad1 + (size_t)n * 4;                         // n
  float* ad2 = as2 + (size_t)n;                             // n
  float* sums = ad2 + (size_t)n;                            // 64*64
  int*  bcnt  = (int*)(sums + 64 * 64);                     // 512 (zeroed w/ sums)
  int*  cur   = bcnt + 512;                                 // 512
  int*  bbase = cur + 512;                                  // 512
  int*  off   = bbase + 512;                                // n+1
  unsigned* packed = (unsigned*)(off + n + 1);              // e
  int*  csr   = (int*)(packed + e);                         // e + 8 slack

  const int eb = (e + CHUNKE - 1) / CHUNKE;                 // 196 blocks

  // CSR build (bucketed two-pass)
  hipMemsetAsync(sums, 0, (64 * 64 + 512) * 4, stream);     // sums + bcnt
  k_bucketcount<<<eb, 256, 0, stream>>>(edst, bcnt, e, NB);
  k_bucketscan <<<1, 512, 0, stream>>>(bcnt, bbase, cur, off, e, n, NB);
  k_partition  <<<eb, 256, 0, stream>>>(esrc, edst, cur, packed, e, NB);
  k_bucketbuild<<<NB, 256, 0, stream>>>(packed, bbase, bcnt, off, csr, n);

  // conv1 (MFMA gemm: 128 rows/block)
  k_gemm_mfma<128, 4, false><<<(n + 127) / 128, 256, 0, stream>>>(
      x, W1, as1w, ad1w, h1, as1, ad1, n);
  k_aggregate<128, 4, true><<<(n + 15) / 16, 256, 0, stream>>>(
      h1, as1, ad1, off, csr, b1, (void*)h1a, n);

  // conv2 (MFMA gemm: 256 rows/block; region reuse)
  unsigned short* h2 = h1;
  float* h2a = (float*)h1a;
  k_gemm_mfma<64, 1, true><<<(n + 255) / 256, 256, 0, stream>>>(
      h1a, W2, as2w, ad2w, h2, as2, ad2, n);
  k_aggregate<64, 1, false><<<(n + 31) / 32, 256, 0, stream>>>(
      h2, as2, ad2, off, csr, b2, (void*)h2a, n);

  // pool + classify
  k_pool_partial<<<(n + 255) / 256, 256, 0, stream>>>(h2a, batch, sums, n);
  k_classify<<<1, 128, 0, stream>>>(sums, batch, Wc, bc, (float*)d_out, n);
}

// Round 3
// 375.873 us; speedup vs baseline: 1.0772x; 1.0011x over previous
//
#include <hip/hip_runtime.h>
#include <math.h>

// ---------------------------------------------------------------------------
// GAT 2-layer + mean-pool + classifier.
//  - CSR(dst): bucketed two-pass build (multisplit), LDS-staged coalesced
//    partition (R2).
//  - softmax denominators factor out; no segment-max (logits O(1), fp32 safe)
//  - message tables bf16
//  - aggregation (R3): each lane-group owns 4 consecutive dsts (Poisson(64)
//    per group -> ~12% less wave imbalance than 1 dst/group)
//  - GEMMs: MFMA 16x16x32 bf16. a_src/a_dst folded into the GEMM as extra
//    B columns (W@att precomputed, bf16 hi+lo split for fp32 accuracy) --
//    kills the 500-op shuffle epilogue (R3).
// ---------------------------------------------------------------------------

typedef __attribute__((ext_vector_type(8))) short bf16x8;
typedef __attribute__((ext_vector_type(4))) float f32x4;

__device__ __forceinline__ unsigned f2bf_rne(float x){
  unsigned u = __float_as_uint(x);
  return (u + 0x7fffu + ((u >> 16) & 1u)) >> 16;
}
__device__ __forceinline__ unsigned pk_bf2(float a, float b){
  return f2bf_rne(a) | (f2bf_rne(b) << 16);
}
__device__ __forceinline__ void unpack8(uint4 q, float* f){
  f[0] = __uint_as_float(q.x << 16);
  f[1] = __uint_as_float(q.x & 0xffff0000u);
  f[2] = __uint_as_float(q.y << 16);
  f[3] = __uint_as_float(q.y & 0xffff0000u);
  f[4] = __uint_as_float(q.z << 16);
  f[5] = __uint_as_float(q.z & 0xffff0000u);
  f[6] = __uint_as_float(q.w << 16);
  f[7] = __uint_as_float(q.w & 0xffff0000u);
}

// ---------------- bucketed CSR build ----------------
// bucket b = dst >> 8 (256 dsts/bucket). NB <= 512.
// packed record: src | (dstoff << 17)  (src < 2^17, dstoff < 256)

#define CHUNKE 8192

__global__ __launch_bounds__(256) void k_bucketcount(
    const int* __restrict__ dst, int* __restrict__ bcnt, int e, int NB)
{
  __shared__ int hcnt[512];
  const int tid = threadIdx.x;
  for (int b = tid; b < 512; b += 256) hcnt[b] = 0;
  __syncthreads();
  const int lo = blockIdx.x * CHUNKE;
  const int hi = min(lo + CHUNKE, e);
  for (int i = lo + tid; i < hi; i += 256)
    atomicAdd(&hcnt[dst[i] >> 8], 1);
  __syncthreads();
  for (int b = tid; b < NB; b += 256)
    if (hcnt[b]) atomicAdd(&bcnt[b], hcnt[b]);
}

// block 0: bucket scan.  block 1: precompute W@att columns (bf16 hi/lo).
__global__ __launch_bounds__(512) void k_bucketscan(
    const int* __restrict__ bcnt, int* __restrict__ bbase,
    int* __restrict__ cur, int* __restrict__ off, int e, int n, int NB,
    const float* __restrict__ W1, const float* __restrict__ as1w,
    const float* __restrict__ ad1w,
    const float* __restrict__ W2, const float* __restrict__ as2w,
    const float* __restrict__ ad2w,
    unsigned short* __restrict__ wa1, unsigned short* __restrict__ wa2)
{
  const int t = threadIdx.x;

  if (blockIdx.x == 1){
    // conv2 table has unused head slots -> zero first
    for (int i = t; i < 2048; i += 512) wa2[i] = 0;
    __syncthreads();
    {
      // conv1: 128 k x 4 heads, CPH=32
      int k = t >> 2, j = t & 3;
      float ds = 0.f, dd = 0.f;
      for (int cc = 0; cc < 32; ++cc){
        float wv = W1[k * 128 + j * 32 + cc];
        ds = fmaf(wv, as1w[j * 32 + cc], ds);
        dd = fmaf(wv, ad1w[j * 32 + cc], dd);
      }
      unsigned hs_ = f2bf_rne(ds); float hsf = __uint_as_float(hs_ << 16);
      unsigned ls_ = f2bf_rne(ds - hsf);
      unsigned hd_ = f2bf_rne(dd); float hdf = __uint_as_float(hd_ << 16);
      unsigned ld_ = f2bf_rne(dd - hdf);
      wa1[(j     ) * 128 + k] = (unsigned short)hs_;
      wa1[(j + 4 ) * 128 + k] = (unsigned short)ls_;
      wa1[(j + 8 ) * 128 + k] = (unsigned short)hd_;
      wa1[(j + 12) * 128 + k] = (unsigned short)ld_;
    }
    if (t < 128){
      // conv2: 128 k x 1 head, CPH=64
      int k = t;
      float ds = 0.f, dd = 0.f;
      for (int cc = 0; cc < 64; ++cc){
        float wv = W2[k * 64 + cc];
        ds = fmaf(wv, as2w[cc], ds);
        dd = fmaf(wv, ad2w[cc], dd);
      }
      unsigned hs_ = f2bf_rne(ds); float hsf = __uint_as_float(hs_ << 16);
      unsigned ls_ = f2bf_rne(ds - hsf);
      unsigned hd_ = f2bf_rne(dd); float hdf = __uint_as_float(hd_ << 16);
      unsigned ld_ = f2bf_rne(dd - hdf);
      wa2[ 0 * 128 + k] = (unsigned short)hs_;
      wa2[ 4 * 128 + k] = (unsigned short)ls_;
      wa2[ 8 * 128 + k] = (unsigned short)hd_;
      wa2[12 * 128 + k] = (unsigned short)ld_;
    }
    return;
  }

  __shared__ int sh[512];
  int v = (t < NB) ? bcnt[t] : 0;
  sh[t] = v;
  __syncthreads();
  for (int o = 1; o < 512; o <<= 1){
    int x = (t >= o) ? sh[t - o] : 0;
    __syncthreads();
    sh[t] += x;
    __syncthreads();
  }
  if (t < NB){
    int excl = sh[t] - v;
    bbase[t] = excl;
    cur[t]   = excl;
  }
  if (t == 0) off[n] = e;
}

// LDS-staged multisplit partition: histogram -> block scan -> LDS scatter
// by bucket -> fully coalesced global writeout of the bucket-sorted chunk.
__global__ __launch_bounds__(256) void k_partition(
    const int* __restrict__ src, const int* __restrict__ dst,
    int* __restrict__ cur, unsigned* __restrict__ packed, int e, int NB)
{
  __shared__ unsigned       recs[CHUNKE];   // 32 KB  bucket-sorted records
  __shared__ unsigned short bkt[CHUNKE];    // 16 KB  bucket id per slot
  __shared__ int hcnt[512];                 // counts, then cursors
  __shared__ int hoff[512];                 // inclusive scan -> exclusive offs
  __shared__ int hbase[512];                // global base per bucket

  const int tid = threadIdx.x;
  const int lo  = blockIdx.x * CHUNKE;
  const int hi  = min(lo + CHUNKE, e);
  const int cnt = hi - lo;

  hcnt[tid] = 0; hcnt[tid + 256] = 0;
  __syncthreads();
  for (int i = lo + tid; i < hi; i += 256)
    atomicAdd(&hcnt[dst[i] >> 8], 1);
  __syncthreads();

  hoff[tid] = hcnt[tid]; hoff[tid + 256] = hcnt[tid + 256];
  __syncthreads();
  for (int o = 1; o < 512; o <<= 1){
    int x0 = (tid >= o)       ? hoff[tid - o]       : 0;
    int x1 = (tid + 256 >= o) ? hoff[tid + 256 - o] : 0;
    __syncthreads();
    hoff[tid] += x0; hoff[tid + 256] += x1;
    __syncthreads();
  }

  int c0 = hcnt[tid], c1 = hcnt[tid + 256];
  int e0 = hoff[tid] - c0, e1 = hoff[tid + 256] - c1;
  hbase[tid]       = c0 ? atomicAdd(&cur[tid], c0)       : 0;
  hbase[tid + 256] = c1 ? atomicAdd(&cur[tid + 256], c1) : 0;
  __syncthreads();
  hoff[tid] = e0; hoff[tid + 256] = e1;
  hcnt[tid] = 0;  hcnt[tid + 256] = 0;
  __syncthreads();

  for (int i = lo + tid; i < hi; i += 256){
    int d = dst[i];
    int b = d >> 8;
    int p = hoff[b] + atomicAdd(&hcnt[b], 1);
    recs[p] = (unsigned)src[i] | ((unsigned)(d & 255) << 17);
    bkt[p]  = (unsigned short)b;
  }
  __syncthreads();

  for (int t = tid; t < cnt; t += 256){
    int b = bkt[t];
    packed[hbase[b] + t - hoff[b]] = recs[t];
  }
}

__global__ __launch_bounds__(256) void k_bucketbuild(
    const unsigned* __restrict__ packed, const int* __restrict__ bbase,
    const int* __restrict__ bcnt, int* __restrict__ off,
    int* __restrict__ csr, int n)
{
  __shared__ int lcnt[256];
  __shared__ int loff[256];
  const int b    = blockIdx.x;
  const int tid  = threadIdx.x;
  const int seg0 = bbase[b];
  const int scnt = bcnt[b];

  lcnt[tid] = 0;
  __syncthreads();
  for (int i = tid; i < scnt; i += 256)
    atomicAdd(&lcnt[packed[seg0 + i] >> 17], 1);
  __syncthreads();
  int v = lcnt[tid];
  loff[tid] = v;
  __syncthreads();
  for (int o = 1; o < 256; o <<= 1){
    int x = (tid >= o) ? loff[tid - o] : 0;
    __syncthreads();
    loff[tid] += x;
    __syncthreads();
  }
  int excl = loff[tid] - v;
  __syncthreads();
  loff[tid] = excl;              // exclusive local offsets
  lcnt[tid] = 0;                 // reuse as cursor
  int d = (b << 8) + tid;
  if (d < n) off[d] = seg0 + excl;
  __syncthreads();
  for (int i = tid; i < scnt; i += 256){
    unsigned rec = packed[seg0 + i];
    int doff = rec >> 17;
    int s    = rec & 0x1FFFF;
    int p    = atomicAdd(&lcnt[doff], 1);
    csr[seg0 + loff[doff] + p] = s;
  }
}

// ---------------- MFMA GEMM (X @ W | W@att columns) ----------------
// B is extended by one 16-col tile carrying a_src/a_dst as bf16 hi/lo pairs:
// col OUTC+j   : hi(W@att_src, head j)    col OUTC+4+j : lo(...)
// col OUTC+8+j : hi(W@att_dst, head j)    col OUTC+12+j: lo(...)
// Epilogue: a = acc + shfl_xor(acc,4); lanes j<HEADS -> ASRC, 8+j -> ADST.

template<int OUTC, int HEADS, bool XBF16, typename XT>
__global__ __launch_bounds__(256) void k_gemm_mfma(
    const XT* __restrict__ X, const float* __restrict__ W,
    const unsigned short* __restrict__ WATT,
    unsigned short* __restrict__ H, float* __restrict__ ASRC,
    float* __restrict__ ADST, int n)
{
  constexpr int K  = 128;
  constexpr int KC = 32;
  constexpr int CT = OUTC / 16;
  constexpr int CTX = CT + 1;          // + att tile
  constexpr int RT = 16 / CT;
  constexpr int WROWS = RT * 16;
  constexpr int BROWS = WROWS * 4;

  __shared__ unsigned short Bs[OUTC + 16][K + 8];
  __shared__ unsigned short As[BROWS][KC + 8];

  const int tid   = threadIdx.x;
  const int lane  = tid & 63;
  const int c15   = lane & 15;
  const int quad  = lane >> 4;
  const int warow = (tid >> 6) * WROWS;
  const int row0  = blockIdx.x * BROWS;

  f32x4 acc[CTX][RT];
  #pragma unroll
  for (int ct = 0; ct < CTX; ++ct)
    #pragma unroll
    for (int t = 0; t < RT; ++t)
      #pragma unroll
      for (int r = 0; r < 4; ++r) acc[ct][t][r] = 0.f;

  for (int idx = tid; idx < K * OUTC / 4; idx += 256){
    int k  = idx / (OUTC / 4);
    int c4 = (idx % (OUTC / 4)) * 4;
    float4 v = *(const float4*)&W[(size_t)k * OUTC + c4];
    Bs[c4 + 0][k] = (unsigned short)f2bf_rne(v.x);
    Bs[c4 + 1][k] = (unsigned short)f2bf_rne(v.y);
    Bs[c4 + 2][k] = (unsigned short)f2bf_rne(v.z);
    Bs[c4 + 3][k] = (unsigned short)f2bf_rne(v.w);
  }
  // att tile columns (precomputed, bf16 hi/lo): WATT is [16][K]
  for (int idx = tid; idx < 16 * (K / 8); idx += 256){
    int rr = idx >> 4;          // K/8 == 16
    int q  = idx & 15;
    *(uint4*)&Bs[OUTC + rr][q * 8] = *(const uint4*)&WATT[rr * K + q * 8];
  }

  for (int kc = 0; kc < K; kc += KC){
    if (XBF16){
      for (int idx = tid; idx < BROWS * (KC / 8); idx += 256){
        int rr = idx / (KC / 8);
        int q  = idx % (KC / 8);
        int row = row0 + rr;
        uint4 v = make_uint4(0, 0, 0, 0);
        if (row < n) v = *(const uint4*)((const unsigned short*)X + (size_t)row * K + kc + q * 8);
        *(uint4*)&As[rr][q * 8] = v;
      }
    } else {
      for (int idx = tid; idx < BROWS * (KC / 4); idx += 256){
        int rr = idx / (KC / 4);
        int q  = idx % (KC / 4);
        int row = row0 + rr;
        float4 v = make_float4(0.f, 0.f, 0.f, 0.f);
        if (row < n) v = *(const float4*)((const float*)X + (size_t)row * K + kc + q * 4);
        *(uint2*)&As[rr][q * 4] = make_uint2(pk_bf2(v.x, v.y), pk_bf2(v.z, v.w));
      }
    }
    __syncthreads();

    bf16x8 af[RT];
    #pragma unroll
    for (int t = 0; t < RT; ++t)
      af[t] = *(const bf16x8*)&As[warow + t * 16 + c15][8 * quad];
    #pragma unroll
    for (int ct = 0; ct < CTX; ++ct){
      bf16x8 bfr = *(const bf16x8*)&Bs[ct * 16 + c15][kc + 8 * quad];
      #pragma unroll
      for (int t = 0; t < RT; ++t)
        acc[ct][t] = __builtin_amdgcn_mfma_f32_16x16x32_bf16(af[t], bfr, acc[ct][t], 0, 0, 0);
    }
    __syncthreads();
  }

  #pragma unroll
  for (int t = 0; t < RT; ++t){
    #pragma unroll
    for (int r = 0; r < 4; ++r){
      int row = row0 + warow + t * 16 + quad * 4 + r;
      float av = acc[CT][t][r];
      av += __shfl_xor(av, 4);          // hi + lo halves
      if (row < n){
        #pragma unroll
        for (int ct = 0; ct < CT; ++ct)
          H[(size_t)row * OUTC + ct * 16 + c15] = (unsigned short)f2bf_rne(acc[ct][t][r]);
        if (c15 < HEADS)                      ASRC[row * HEADS + c15] = av;
        else if (c15 >= 8 && c15 < 8 + HEADS) ADST[row * HEADS + c15 - 8] = av;
      }
    }
  }
}

// ---------------- dst-centric aggregation + bias + ELU ----------------
// One CL-lane group owns DSTS consecutive dsts (balance: Poisson(16*DSTS));
// per dst: self-loop init, unmasked full 8-rounds, masked tail round.

template<int CH, int HEADS, bool OUTBF16, int DSTS>
__global__ __launch_bounds__(256) void k_aggregate(
    const unsigned short* __restrict__ Hmsg, const float* __restrict__ ASRC,
    const float* __restrict__ ADST, const int* __restrict__ off,
    const int* __restrict__ csr, const float* __restrict__ bias,
    void* __restrict__ OUT, int n)
{
  constexpr int CL  = CH / 8;       // lanes per dst-group
  constexpr int GPB = 256 / CL;     // groups per block
  constexpr int CPH = CH / HEADS;
  constexpr int RQ  = CH / 8;       // uint4 per bf16 row

  const int tid = threadIdx.x;
  const int cl  = tid % CL;
  const int c0  = cl * 8;
  const int h   = c0 / CPH;
  const int g   = blockIdx.x * GPB + tid / CL;
  const uint4* Hv = (const uint4*)Hmsg;

  float bv[8];
  #pragma unroll
  for (int j = 0; j < 8; ++j) bv[j] = bias[c0 + j];

  #pragma unroll 1
  for (int it = 0; it < DSTS; ++it){
    const int d = g * DSTS + it;
    if (d >= n) break;

    const float adst = ADST[d * HEADS + h];

    float acc[8];
    float wsum;
    {
      float t = ASRC[d * HEADS + h] + adst;
      float w = __expf(fmaxf(t, 0.2f * t));
      float f[8];
      unpack8(Hv[d * RQ + cl], f);
      #pragma unroll
      for (int j = 0; j < 8; ++j) acc[j] = w * f[j];
      wsum = w;
    }

    const int s0   = off[d];
    const int cnt  = off[d + 1] - s0;
    const int full = cnt & ~7;

    for (int p = 0; p < full; p += 8){
      int idx[8];
      #pragma unroll
      for (int j = 0; j < 8; ++j) idx[j] = csr[s0 + p + j];
      float av[8];
      #pragma unroll
      for (int j = 0; j < 8; ++j) av[j] = ASRC[idx[j] * HEADS + h];
      uint4 hq[8];
      #pragma unroll
      for (int j = 0; j < 8; ++j) hq[j] = Hv[idx[j] * RQ + cl];
      #pragma unroll
      for (int j = 0; j < 8; ++j){
        float t = av[j] + adst;
        float w = __expf(fmaxf(t, 0.2f * t));
        float f[8];
        unpack8(hq[j], f);
        #pragma unroll
        for (int q = 0; q < 8; ++q) acc[q] = fmaf(w, f[q], acc[q]);
        wsum += w;
      }
    }

    const int rem = cnt - full;
    if (rem){
      int  idx[8];
      bool ok[8];
      #pragma unroll
      for (int j = 0; j < 8; ++j){
        int q = csr[s0 + full + j];     // csr has +8 slack
        ok[j]  = j < rem;
        idx[j] = ok[j] ? q : 0;
      }
      float av[8];
      #pragma unroll
      for (int j = 0; j < 8; ++j) av[j] = ASRC[idx[j] * HEADS + h];
      uint4 hq[8];
      #pragma unroll
      for (int j = 0; j < 8; ++j) hq[j] = Hv[idx[j] * RQ + cl];
      #pragma unroll
      for (int j = 0; j < 8; ++j){
        float t = av[j] + adst;
        float w = __expf(fmaxf(t, 0.2f * t));
        w = ok[j] ? w : 0.f;
        float f[8];
        unpack8(hq[j], f);
        #pragma unroll
        for (int q = 0; q < 8; ++q) acc[q] = fmaf(w, f[q], acc[q]);
        wsum += w;
      }
    }

    const float inv = 1.f / (wsum + 1e-16f);
    float o[8];
    #pragma unroll
    for (int j = 0; j < 8; ++j){
      float v = acc[j] * inv + bv[j];
      o[j] = v > 0.f ? v : expm1f(v);
    }
    if (OUTBF16){
      uint4 q;
      q.x = pk_bf2(o[0], o[1]); q.y = pk_bf2(o[2], o[3]);
      q.z = pk_bf2(o[4], o[5]); q.w = pk_bf2(o[6], o[7]);
      *(uint4*)((unsigned short*)OUT + (size_t)d * CH + c0) = q;
    } else {
      float* Of = (float*)OUT;
      *(float4*)&Of[(size_t)d * CH + c0 + 0] = make_float4(o[0], o[1], o[2], o[3]);
      *(float4*)&Of[(size_t)d * CH + c0 + 4] = make_float4(o[4], o[5], o[6], o[7]);
    }
  }
}

// ---------------- pooling: chunk-parallel partial sums ----------------

__global__ __launch_bounds__(256) void k_pool_partial(
    const float* __restrict__ H, const int* __restrict__ batch,
    float* __restrict__ sums, int n)
{
  constexpr int CHUNK = 256;
  const int c    = threadIdx.x & 63;
  const int slot = threadIdx.x >> 6;
  const int start = blockIdx.x * CHUNK;
  const int end   = min(start + CHUNK, n);

  float acc = 0.f;
  int cur = -1;
  for (int nn = start + slot; nn < end; nn += 4){
    int g = batch[nn];
    if (g != cur){
      if (cur >= 0) atomicAdd(&sums[cur * 64 + c], acc);
      acc = 0.f; cur = g;
    }
    acc += H[(size_t)nn * 64 + c];
  }
  if (cur >= 0) atomicAdd(&sums[cur * 64 + c], acc);
}

__global__ __launch_bounds__(128) void k_classify(
    const float* __restrict__ sums, const int* __restrict__ batch,
    const float* __restrict__ Wc, const float* __restrict__ bc,
    float* __restrict__ out, int n)
{
  int t = threadIdx.x;
  if (t >= 128) return;
  int g = t >> 1, cls = t & 1;
  int lo = 0, hi = n;
  while (lo < hi){ int m = (lo + hi) >> 1; if (batch[m] < g) lo = m + 1; else hi = m; }
  int s = lo;
  lo = s; hi = n;
  while (lo < hi){ int m = (lo + hi) >> 1; if (batch[m] < g + 1) lo = m + 1; else hi = m; }
  int cnt = lo - s;
  float inv = 1.f / (float)(cnt > 1 ? cnt : 1);
  float dot = 0.f;
  #pragma unroll
  for (int c = 0; c < 64; ++c) dot = fmaf(sums[g * 64 + c], Wc[c * 2 + cls], dot);
  out[g * 2 + cls] = dot * inv + bc[cls];
}

// ---------------- launch ----------------

extern "C" void kernel_launch(void* const* d_in, const int* in_sizes, int n_in,
                              void* d_out, int out_size, void* d_ws, size_t ws_size,
                              hipStream_t stream)
{
  const float* x    = (const float*)d_in[0];
  const int*   edge = (const int*)  d_in[1];
  const int*   batch= (const int*)  d_in[2];
  const float* W1   = (const float*)d_in[3];
  const float* as1w = (const float*)d_in[4];
  const float* ad1w = (const float*)d_in[5];
  const float* b1   = (const float*)d_in[6];
  const float* W2   = (const float*)d_in[7];
  const float* as2w = (const float*)d_in[8];
  const float* ad2w = (const float*)d_in[9];
  const float* b2   = (const float*)d_in[10];
  const float* Wc   = (const float*)d_in[11];
  const float* bc   = (const float*)d_in[12];

  const int n = in_sizes[2];          // 100000
  const int e = in_sizes[1] / 2;      // 1600000
  const int* esrc = edge;
  const int* edst = edge + e;
  const int NB = (n + 255) >> 8;      // 391 buckets

  // workspace layout
  unsigned short* h1  = (unsigned short*)d_ws;              // n*128 bf16 (later h2 n*64)
  unsigned short* h1a = h1 + (size_t)n * 128;               // n*128 bf16 (later h2a n*64 f32)
  float* as1 = (float*)(h1a + (size_t)n * 128);             // n*4
  float* ad1 = as1 + (size_t)n * 4;                         // n*4
  float* as2 = ad1 + (size_t)n * 4;                         // n
  float* ad2 = as2 + (size_t)n;                             // n
  float* sums = ad2 + (size_t)n;                            // 64*64
  unsigned short* wa1 = (unsigned short*)(sums + 64 * 64);  // [16][128] bf16
  unsigned short* wa2 = wa1 + 2048;                         // [16][128] bf16
  int*  bcnt  = (int*)(wa2 + 2048);                         // 512 (zeroed w/ sums)
  int*  cur   = bcnt + 512;                                 // 512
  int*  bbase = cur + 512;                                  // 512
  int*  off   = bbase + 512;                                // n+1
  unsigned* packed = (unsigned*)(off + n + 1);              // e
  int*  csr   = (int*)(packed + e);                         // e + 8 slack

  const int eb = (e + CHUNKE - 1) / CHUNKE;                 // 196 blocks

  // CSR build (bucketed two-pass); block 1 of bucketscan = W@att precompute
  hipMemsetAsync(sums, 0, 64 * 64 * 4 + 2 * 4096 + 512 * 4, stream);
  k_bucketcount<<<eb, 256, 0, stream>>>(edst, bcnt, e, NB);
  k_bucketscan <<<2, 512, 0, stream>>>(bcnt, bbase, cur, off, e, n, NB,
                                       W1, as1w, ad1w, W2, as2w, ad2w, wa1, wa2);
  k_partition  <<<eb, 256, 0, stream>>>(esrc, edst, cur, packed, e, NB);
  k_bucketbuild<<<NB, 256, 0, stream>>>(packed, bbase, bcnt, off, csr, n);

  // conv1 (MFMA gemm: 128 rows/block)
  k_gemm_mfma<128, 4, false><<<(n + 127) / 128, 256, 0, stream>>>(
      x, W1, wa1, h1, as1, ad1, n);
  k_aggregate<128, 4, true, 4><<<(n + 63) / 64, 256, 0, stream>>>(
      h1, as1, ad1, off, csr, b1, (void*)h1a, n);

  // conv2 (MFMA gemm: 256 rows/block; region reuse)
  unsigned short* h2 = h1;
  float* h2a = (float*)h1a;
  k_gemm_mfma<64, 1, true><<<(n + 255) / 256, 256, 0, stream>>>(
      h1a, W2, wa2, h2, as2, ad2, n);
  k_aggregate<64, 1, false, 4><<<(n + 127) / 128, 256, 0, stream>>>(
      h2, as2, ad2, off, csr, b2, (void*)h2a, n);

  // pool + classify
  k_pool_partial<<<(n + 255) / 256, 256, 0, stream>>>(h2a, batch, sums, n);
  k_classify<<<1, 128, 0, stream>>>(sums, batch, Wc, bc, (float*)d_out, n);
}